// Round 1
// baseline (167.806 us; speedup 1.0000x reference)
//
#include <hip/hip_runtime.h>

#define IMG   512
#define NIMG  64
#define TS_R  32            // output tile rows
#define TS_C  64            // output tile cols
#define HALO  5
#define IN_R  (TS_R + 2*HALO)   // 42
#define IN_C  76                // 74 needed, padded to 76 (16B-multiple row stride: 304B)
#define NBLK  (NIMG * (IMG/TS_R) * (IMG/TS_C))   // 64*16*8 = 8192

#define C1F   1.0e-4f
#define C2F   9.0e-4f

__global__ __launch_bounds__(256, 2)
void ssim_main(const float* __restrict__ x, const float* __restrict__ y,
               float* __restrict__ partial) {
    __shared__ __align__(16) float xs[IN_R][IN_C];
    __shared__ __align__(16) float ys[IN_R][IN_C];
    __shared__ __align__(16) float Hf[5][IN_R][TS_C];   // hx, hy, hxx, hyy, hxy
    __shared__ float red[4];

    const int tid = threadIdx.x;

    // Gaussian window (matches jnp: exp(-d^2/(2*1.5^2)) normalized), fp32.
    float w[11];
    {
        float s = 0.0f;
        #pragma unroll
        for (int k = 0; k < 11; ++k) {
            float d = (float)(k - 5);
            w[k] = expf(-d * d * (1.0f / 4.5f));
            s += w[k];
        }
        float inv = 1.0f / s;
        #pragma unroll
        for (int k = 0; k < 11; ++k) w[k] *= inv;
    }

    const int img = blockIdx.z;
    const int r0  = blockIdx.y * TS_R;
    const int c0  = blockIdx.x * TS_C;
    const float* xb = x + (size_t)img * IMG * IMG;
    const float* yb = y + (size_t)img * IMG * IMG;

    // ---- Phase 1: stage raw tiles (zero-padded) ----
    for (int idx = tid; idx < IN_R * IN_C; idx += 256) {
        int i = idx / IN_C;
        int j = idx - i * IN_C;
        int gr = r0 - HALO + i;
        int gc = c0 - HALO + j;
        bool ok = (gr >= 0) & (gr < IMG) & (gc >= 0) & (gc < IMG);
        size_t off = (size_t)gr * IMG + gc;
        xs[i][j] = ok ? xb[off] : 0.0f;
        ys[i][j] = ok ? yb[off] : 0.0f;
    }
    __syncthreads();

    // ---- Phase 2: horizontal 11-tap for 5 fields, 4-col register blocking ----
    for (int g = tid; g < IN_R * (TS_C / 4); g += 256) {   // 42*16 = 672 groups
        int i   = g >> 4;
        int cc0 = (g & 15) * 4;
        float rx[16], ry[16];
        #pragma unroll
        for (int q = 0; q < 4; ++q) {
            float4 vx4 = *(const float4*)&xs[i][cc0 + 4 * q];
            rx[4*q+0] = vx4.x; rx[4*q+1] = vx4.y; rx[4*q+2] = vx4.z; rx[4*q+3] = vx4.w;
            float4 vy4 = *(const float4*)&ys[i][cc0 + 4 * q];
            ry[4*q+0] = vy4.x; ry[4*q+1] = vy4.y; ry[4*q+2] = vy4.z; ry[4*q+3] = vy4.w;
        }
        float hx[4], hy[4], hxx[4], hyy[4], hxy[4];
        #pragma unroll
        for (int cc = 0; cc < 4; ++cc) { hx[cc]=0.f; hy[cc]=0.f; hxx[cc]=0.f; hyy[cc]=0.f; hxy[cc]=0.f; }
        #pragma unroll
        for (int cc = 0; cc < 4; ++cc) {
            #pragma unroll
            for (int k = 0; k < 11; ++k) {
                float xa = rx[cc + k], ya = ry[cc + k];
                float t = w[k] * xa;
                float u = w[k] * ya;
                hx[cc] += t;
                hy[cc] += u;
                hxx[cc] = fmaf(t, xa, hxx[cc]);
                hyy[cc] = fmaf(u, ya, hyy[cc]);
                hxy[cc] = fmaf(t, ya, hxy[cc]);
            }
        }
        *(float4*)&Hf[0][i][cc0] = make_float4(hx[0],  hx[1],  hx[2],  hx[3]);
        *(float4*)&Hf[1][i][cc0] = make_float4(hy[0],  hy[1],  hy[2],  hy[3]);
        *(float4*)&Hf[2][i][cc0] = make_float4(hxx[0], hxx[1], hxx[2], hxx[3]);
        *(float4*)&Hf[3][i][cc0] = make_float4(hyy[0], hyy[1], hyy[2], hyy[3]);
        *(float4*)&Hf[4][i][cc0] = make_float4(hxy[0], hxy[1], hxy[2], hxy[3]);
    }
    __syncthreads();

    // ---- Phase 3: vertical 11-tap, 2 rows x 4 cols per thread, SSIM epilogue ----
    float ssum = 0.0f;
    {
        const int rg = tid >> 4;          // 0..15
        const int cg = tid & 15;          // 0..15
        const int rr = rg * 2;            // output row base in tile
        const int cc = cg * 4;            // output col base in tile
        float4 a0[5], a1[5];
        #pragma unroll
        for (int f = 0; f < 5; ++f) {
            a0[f] = make_float4(0.f, 0.f, 0.f, 0.f);
            a1[f] = make_float4(0.f, 0.f, 0.f, 0.f);
        }
        #pragma unroll
        for (int j = 0; j < 12; ++j) {
            #pragma unroll
            for (int f = 0; f < 5; ++f) {
                float4 h = *(const float4*)&Hf[f][rr + j][cc];
                if (j < 11) {
                    float wk = w[j];
                    a0[f].x = fmaf(wk, h.x, a0[f].x);
                    a0[f].y = fmaf(wk, h.y, a0[f].y);
                    a0[f].z = fmaf(wk, h.z, a0[f].z);
                    a0[f].w = fmaf(wk, h.w, a0[f].w);
                }
                if (j >= 1) {
                    float wk = w[j - 1];
                    a1[f].x = fmaf(wk, h.x, a1[f].x);
                    a1[f].y = fmaf(wk, h.y, a1[f].y);
                    a1[f].z = fmaf(wk, h.z, a1[f].z);
                    a1[f].w = fmaf(wk, h.w, a1[f].w);
                }
            }
        }
        #pragma unroll
        for (int row = 0; row < 2; ++row) {
            float4* a = (row == 0) ? a0 : a1;
            #pragma unroll
            for (int e = 0; e < 4; ++e) {
                float mx  = ((const float*)&a[0])[e];
                float my  = ((const float*)&a[1])[e];
                float exx = ((const float*)&a[2])[e];
                float eyy = ((const float*)&a[3])[e];
                float exy = ((const float*)&a[4])[e];
                float mxx = mx * mx, myy = my * my, mxy = mx * my;
                float vx  = exx - mxx;
                float vy  = eyy - myy;
                float vxy = exy - mxy;
                float num = (2.0f * mxy + C1F) * (2.0f * vxy + C2F);
                float den = (mxx + myy + C1F) * (vx + vy + C2F);
                ssum += num / den;
            }
        }
    }

    // ---- Block reduction (deterministic) ----
    #pragma unroll
    for (int off = 32; off > 0; off >>= 1)
        ssum += __shfl_down(ssum, off, 64);
    if ((tid & 63) == 0) red[tid >> 6] = ssum;
    __syncthreads();
    if (tid == 0) {
        float tot = red[0] + red[1] + red[2] + red[3];
        int bi = (blockIdx.z * gridDim.y + blockIdx.y) * gridDim.x + blockIdx.x;
        partial[bi] = tot;
    }
}

__global__ __launch_bounds__(1024)
void ssim_final(const float* __restrict__ partial, float* __restrict__ out) {
    __shared__ float red[16];
    float s = 0.0f;
    for (int i = threadIdx.x; i < NBLK; i += 1024) s += partial[i];
    #pragma unroll
    for (int off = 32; off > 0; off >>= 1)
        s += __shfl_down(s, off, 64);
    if ((threadIdx.x & 63) == 0) red[threadIdx.x >> 6] = s;
    __syncthreads();
    if (threadIdx.x == 0) {
        float tot = 0.0f;
        #pragma unroll
        for (int i = 0; i < 16; ++i) tot += red[i];
        out[0] = 1.0f - tot * (1.0f / 16777216.0f);
    }
}

extern "C" void kernel_launch(void* const* d_in, const int* in_sizes, int n_in,
                              void* d_out, int out_size, void* d_ws, size_t ws_size,
                              hipStream_t stream) {
    const float* x = (const float*)d_in[0];
    const float* y = (const float*)d_in[1];
    float* out     = (float*)d_out;
    float* partial = (float*)d_ws;   // NBLK floats = 32 KB

    dim3 grid(IMG / TS_C, IMG / TS_R, NIMG);   // (8, 16, 64)
    ssim_main<<<grid, 256, 0, stream>>>(x, y, partial);
    ssim_final<<<1, 1024, 0, stream>>>(partial, out);
}

// Round 2
// 131.408 us; speedup vs baseline: 1.2770x; 1.2770x over previous
//
#include <hip/hip_runtime.h>
#include <hip/hip_fp16.h>

#define IMG   512
#define NIMG  64
#define TS_R  32
#define TS_C  64
#define HALO  5
#define IN_R  (TS_R + 2*HALO)      // 42
#define IN_C  (TS_C + 2*HALO)      // 74
#define NBLK  (NIMG * (IMG/TS_R) * (IMG/TS_C))   // 8192
#define HFSTRIDE (IN_R * (TS_C/2))               // u32 per field = 1344

#define C1F   1.0e-4f
#define C2F   9.0e-4f

__device__ __forceinline__ uint pack_h2(float a, float b) {
    __half2 h = __floats2half2_rn(a, b);
    return *reinterpret_cast<uint*>(&h);
}
__device__ __forceinline__ float2 unpack_h2(uint u) {
    __half2 h = *reinterpret_cast<__half2*>(&u);
    return make_float2(__low2float(h), __high2float(h));
}

__global__ __launch_bounds__(256, 4)
void ssim_main(const float* __restrict__ x, const float* __restrict__ y,
               float* __restrict__ partial) {
    __shared__ uint xy16[IN_R * IN_C];        // packed (x,y) half2      : 12432 B
    __shared__ uint Hq[5 * HFSTRIDE];         // 5 fp16 fields, swizzled : 26880 B
    __shared__ float red[4];

    const int tid = threadIdx.x;

    // Gaussian window (matches jnp: exp(-d^2/4.5) normalized), fp32.
    float w[11];
    {
        float s = 0.0f;
        #pragma unroll
        for (int k = 0; k < 11; ++k) {
            float d = (float)(k - 5);
            w[k] = expf(-d * d * (1.0f / 4.5f));
            s += w[k];
        }
        float inv = 1.0f / s;
        #pragma unroll
        for (int k = 0; k < 11; ++k) w[k] *= inv;
    }

    const int img = blockIdx.z;
    const int r0  = blockIdx.y * TS_R;
    const int c0  = blockIdx.x * TS_C;
    const float* xb = x + (size_t)img * IMG * IMG;
    const float* yb = y + (size_t)img * IMG * IMG;

    // ---- Phase 1: stage packed fp16 (x,y) with zero padding ----
    for (int idx = tid; idx < IN_R * IN_C; idx += 256) {
        int i = idx / IN_C;
        int j = idx - i * IN_C;
        int gr = r0 - HALO + i;
        int gc = c0 - HALO + j;
        bool ok = (gr >= 0) & (gr < IMG) & (gc >= 0) & (gc < IMG);
        size_t off = (size_t)gr * IMG + gc;
        float xv = ok ? xb[off] : 0.0f;
        float yv = ok ? yb[off] : 0.0f;
        xy16[idx] = pack_h2(xv, yv);
    }
    __syncthreads();

    // ---- Phase 2: horizontal 11-tap, 4 outputs per group, j-outer ----
    for (int g = tid; g < IN_R * (TS_C / 4); g += 256) {   // 672 groups
        int i   = g >> 4;
        int cc0 = (g & 15) << 2;
        const uint* rowp = &xy16[i * IN_C + cc0];
        float hx[4]  = {0.f,0.f,0.f,0.f};
        float hy[4]  = {0.f,0.f,0.f,0.f};
        float hxx[4] = {0.f,0.f,0.f,0.f};
        float hyy[4] = {0.f,0.f,0.f,0.f};
        float hxy[4] = {0.f,0.f,0.f,0.f};
        #pragma unroll
        for (int j = 0; j < 14; ++j) {
            float2 v = unpack_h2(rowp[j]);
            float xv = v.x, yv = v.y;
            float xxv = xv * xv, yyv = yv * yv, xyv = xv * yv;
            #pragma unroll
            for (int cc = 0; cc < 4; ++cc) {
                if (j - cc >= 0 && j - cc <= 10) {
                    float wk = w[j - cc];
                    hx[cc]  = fmaf(wk, xv,  hx[cc]);
                    hy[cc]  = fmaf(wk, yv,  hy[cc]);
                    hxx[cc] = fmaf(wk, xxv, hxx[cc]);
                    hyy[cc] = fmaf(wk, yyv, hyy[cc]);
                    hxy[cc] = fmaf(wk, xyv, hxy[cc]);
                }
            }
        }
        int base = i * (TS_C / 2) + (cc0 >> 1);
        int idx  = (base ^ ((i & 7) << 2));
        uint2 v;
        v.x = pack_h2(hx[0], hx[1]);  v.y = pack_h2(hx[2], hx[3]);
        *(uint2*)&Hq[0 * HFSTRIDE + idx] = v;
        v.x = pack_h2(hy[0], hy[1]);  v.y = pack_h2(hy[2], hy[3]);
        *(uint2*)&Hq[1 * HFSTRIDE + idx] = v;
        v.x = pack_h2(hxx[0], hxx[1]); v.y = pack_h2(hxx[2], hxx[3]);
        *(uint2*)&Hq[2 * HFSTRIDE + idx] = v;
        v.x = pack_h2(hyy[0], hyy[1]); v.y = pack_h2(hyy[2], hyy[3]);
        *(uint2*)&Hq[3 * HFSTRIDE + idx] = v;
        v.x = pack_h2(hxy[0], hxy[1]); v.y = pack_h2(hxy[2], hxy[3]);
        *(uint2*)&Hq[4 * HFSTRIDE + idx] = v;
    }
    __syncthreads();

    // ---- Phase 3: vertical 11-tap, thread = 1 row x 8 cols, fp32 accum ----
    float ssum = 0.0f;
    {
        const int rg = tid >> 3;       // output row 0..31
        const int cg = tid & 7;        // col group (8 cols)
        float acc[5][8];
        #pragma unroll
        for (int f = 0; f < 5; ++f)
            #pragma unroll
            for (int e = 0; e < 8; ++e) acc[f][e] = 0.0f;

        #pragma unroll
        for (int j = 0; j < 11; ++j) {
            int row  = rg + j;
            int idx0 = (row * (TS_C / 2) + (cg << 2)) ^ ((row & 7) << 2);
            float wk = w[j];
            #pragma unroll
            for (int f = 0; f < 5; ++f) {
                uint4 q = *(const uint4*)&Hq[f * HFSTRIDE + idx0];
                float2 p0 = unpack_h2(q.x);
                float2 p1 = unpack_h2(q.y);
                float2 p2 = unpack_h2(q.z);
                float2 p3 = unpack_h2(q.w);
                acc[f][0] = fmaf(wk, p0.x, acc[f][0]);
                acc[f][1] = fmaf(wk, p0.y, acc[f][1]);
                acc[f][2] = fmaf(wk, p1.x, acc[f][2]);
                acc[f][3] = fmaf(wk, p1.y, acc[f][3]);
                acc[f][4] = fmaf(wk, p2.x, acc[f][4]);
                acc[f][5] = fmaf(wk, p2.y, acc[f][5]);
                acc[f][6] = fmaf(wk, p3.x, acc[f][6]);
                acc[f][7] = fmaf(wk, p3.y, acc[f][7]);
            }
        }
        #pragma unroll
        for (int e = 0; e < 8; ++e) {
            float mx  = acc[0][e];
            float my  = acc[1][e];
            float exx = acc[2][e];
            float eyy = acc[3][e];
            float exy = acc[4][e];
            float mxx = mx * mx, myy = my * my, mxy = mx * my;
            float vx  = exx - mxx;
            float vy  = eyy - myy;
            float vxy = exy - mxy;
            float num = (2.0f * mxy + C1F) * (2.0f * vxy + C2F);
            float den = (mxx + myy + C1F) * (vx + vy + C2F);
            ssum = fmaf(num, __builtin_amdgcn_rcpf(den), ssum);
        }
    }

    // ---- Block reduction (deterministic) ----
    #pragma unroll
    for (int off = 32; off > 0; off >>= 1)
        ssum += __shfl_down(ssum, off, 64);
    if ((tid & 63) == 0) red[tid >> 6] = ssum;
    __syncthreads();
    if (tid == 0) {
        float tot = red[0] + red[1] + red[2] + red[3];
        int bi = (blockIdx.z * gridDim.y + blockIdx.y) * gridDim.x + blockIdx.x;
        partial[bi] = tot;
    }
}

__global__ __launch_bounds__(1024)
void ssim_final(const float* __restrict__ partial, float* __restrict__ out) {
    __shared__ float red[16];
    float s = 0.0f;
    for (int i = threadIdx.x; i < NBLK; i += 1024) s += partial[i];
    #pragma unroll
    for (int off = 32; off > 0; off >>= 1)
        s += __shfl_down(s, off, 64);
    if ((threadIdx.x & 63) == 0) red[threadIdx.x >> 6] = s;
    __syncthreads();
    if (threadIdx.x == 0) {
        float tot = 0.0f;
        #pragma unroll
        for (int i = 0; i < 16; ++i) tot += red[i];
        out[0] = 1.0f - tot * (1.0f / 16777216.0f);
    }
}

extern "C" void kernel_launch(void* const* d_in, const int* in_sizes, int n_in,
                              void* d_out, int out_size, void* d_ws, size_t ws_size,
                              hipStream_t stream) {
    const float* x = (const float*)d_in[0];
    const float* y = (const float*)d_in[1];
    float* out     = (float*)d_out;
    float* partial = (float*)d_ws;   // NBLK floats = 32 KB

    dim3 grid(IMG / TS_C, IMG / TS_R, NIMG);   // (8, 16, 64)
    ssim_main<<<grid, 256, 0, stream>>>(x, y, partial);
    ssim_final<<<1, 1024, 0, stream>>>(partial, out);
}

// Round 3
// 128.629 us; speedup vs baseline: 1.3046x; 1.0216x over previous
//
#include <hip/hip_runtime.h>
#include <hip/hip_fp16.h>

#define IMG   512
#define NIMG  64
#define TS_R  32
#define TS_C  64
#define HALO  5
#define IN_R  (TS_R + 2*HALO)      // 42
#define IN_C  76                   // 74 needed, padded to 76 (16B-aligned rows for b128)
#define NBLK  (NIMG * (IMG/TS_R) * (IMG/TS_C))   // 8192

#define C1F   1.0e-4f
#define C2F   9.0e-4f

__device__ __forceinline__ __half2 h2(uint u)   { return *reinterpret_cast<__half2*>(&u); }
__device__ __forceinline__ uint    u32(__half2 h){ return *reinterpret_cast<uint*>(&h); }

// Column swizzle for 64-wide (u32) field rows: XOR row bits into bank bits 2..4,
// and fold col bit5 into bit2 so cg*8 strides cover all 32 banks. Involution per (row, col-bit5).
__device__ __forceinline__ int swz64(int row, int col) {
    return col ^ ((row & 7) << 2) ^ (((col >> 5) & 1) << 2);
}

__global__ __launch_bounds__(256, 4)
void ssim_main(const float* __restrict__ x, const float* __restrict__ y,
               float* __restrict__ partial) {
    __shared__ uint xy16[IN_R * IN_C];       // packed (x,y) half2        12768 B
    __shared__ uint Hmu[IN_R * TS_C];        // (hx,hy)  half2, swizzled  10752 B
    __shared__ uint Hsq[IN_R * TS_C];        // (hxx,hyy) half2, swizzled 10752 B
    __shared__ uint Hxy[IN_R * (TS_C/2)];    // hxy half, 2 px/u32         5376 B
    __shared__ float red[4];

    const int tid = threadIdx.x;

    // Gaussian window (matches jnp: exp(-d^2/4.5) normalized), fp32 -> fp16.
    float w[11];
    {
        float s = 0.0f;
        #pragma unroll
        for (int k = 0; k < 11; ++k) {
            float d = (float)(k - 5);
            w[k] = expf(-d * d * (1.0f / 4.5f));
            s += w[k];
        }
        float inv = 1.0f / s;
        #pragma unroll
        for (int k = 0; k < 11; ++k) w[k] *= inv;
    }
    __half2 wh2[11];
    __half  wh[11];
    #pragma unroll
    for (int k = 0; k < 11; ++k) {
        wh[k]  = __float2half(w[k]);
        wh2[k] = __half2half2(wh[k]);
    }

    const int img = blockIdx.z;
    const int r0  = blockIdx.y * TS_R;
    const int c0  = blockIdx.x * TS_C;
    const float* xb = x + (size_t)img * IMG * IMG;
    const float* yb = y + (size_t)img * IMG * IMG;

    // ---- Phase 1: stage packed fp16 (x,y), zero-padded ----
    for (int idx = tid; idx < IN_R * IN_C; idx += 256) {
        int i = idx / IN_C;
        int j = idx - i * IN_C;
        int gr = r0 - HALO + i;
        int gc = c0 - HALO + j;
        bool ok = (gr >= 0) & (gr < IMG) & (gc >= 0) & (gc < IMG);
        size_t off = (size_t)gr * IMG + gc;
        float xv = ok ? xb[off] : 0.0f;
        float yv = ok ? yb[off] : 0.0f;
        __half2 p = __floats2half2_rn(xv, yv);
        xy16[idx] = u32(p);
    }
    __syncthreads();

    // ---- Phase 2: horizontal 11-tap, packed fp16, 4 outputs/group ----
    for (int g = tid; g < IN_R * (TS_C / 4); g += 256) {   // 672 groups
        int i   = g >> 4;
        int cc0 = (g & 15) << 2;
        const uint* rowp = &xy16[i * IN_C + cc0];
        uint4 q0 = *(const uint4*)&rowp[0];
        uint4 q1 = *(const uint4*)&rowp[4];
        uint4 q2 = *(const uint4*)&rowp[8];
        uint2 q3 = *(const uint2*)&rowp[12];
        uint raw[14] = {q0.x,q0.y,q0.z,q0.w, q1.x,q1.y,q1.z,q1.w,
                        q2.x,q2.y,q2.z,q2.w, q3.x,q3.y};
        __half2 vj[14], sj[14];
        __half  xj[14];
        #pragma unroll
        for (int j = 0; j < 14; ++j) {
            __half2 v = h2(raw[j]);
            vj[j] = v;
            sj[j] = __hmul2(v, v);
            xj[j] = __hmul(__low2half(v), __high2half(v));
        }
        __half2 accm[4], accs[4];
        __half  accx[4];
        #pragma unroll
        for (int cc = 0; cc < 4; ++cc) {
            accm[cc] = __half2half2(__half(0.0f));
            accs[cc] = __half2half2(__half(0.0f));
            accx[cc] = __half(0.0f);
        }
        #pragma unroll
        for (int cc = 0; cc < 4; ++cc) {
            #pragma unroll
            for (int k = 0; k < 11; ++k) {
                accm[cc] = __hfma2(wh2[k], vj[cc + k], accm[cc]);
                accs[cc] = __hfma2(wh2[k], sj[cc + k], accs[cc]);
                accx[cc] = __hfma (wh[k],  xj[cc + k], accx[cc]);
            }
        }
        int bm = i * TS_C + swz64(i, cc0);
        *(uint4*)&Hmu[bm] = make_uint4(u32(accm[0]), u32(accm[1]), u32(accm[2]), u32(accm[3]));
        *(uint4*)&Hsq[bm] = make_uint4(u32(accs[0]), u32(accs[1]), u32(accs[2]), u32(accs[3]));
        int bx = i * (TS_C/2) + (((cc0 >> 1)) ^ ((i & 7) << 2));
        __half2 xa = __halves2half2(accx[0], accx[1]);
        __half2 xbp = __halves2half2(accx[2], accx[3]);
        *(uint2*)&Hxy[bx] = make_uint2(u32(xa), u32(xbp));
    }
    __syncthreads();

    // ---- Phase 3: vertical 11-tap packed fp16, thread = 1 row x 8 cols ----
    float ssum = 0.0f;
    {
        const int rg = tid >> 3;       // output row 0..31
        const int cg = tid & 7;        // col group (8 cols)
        __half2 am[8], as[8], ax[4];
        #pragma unroll
        for (int e = 0; e < 8; ++e) { am[e] = __half2half2(__half(0.0f)); as[e] = am[e]; }
        #pragma unroll
        for (int e = 0; e < 4; ++e) ax[e] = __half2half2(__half(0.0f));

        #pragma unroll
        for (int j = 0; j < 11; ++j) {
            int row = rg + j;
            __half2 w2 = wh2[j];
            int sA = row * TS_C + swz64(row, cg * 8);
            uint4 m0 = *(const uint4*)&Hmu[sA];
            uint4 m1 = *(const uint4*)&Hmu[sA ^ 4];
            am[0] = __hfma2(w2, h2(m0.x), am[0]);
            am[1] = __hfma2(w2, h2(m0.y), am[1]);
            am[2] = __hfma2(w2, h2(m0.z), am[2]);
            am[3] = __hfma2(w2, h2(m0.w), am[3]);
            am[4] = __hfma2(w2, h2(m1.x), am[4]);
            am[5] = __hfma2(w2, h2(m1.y), am[5]);
            am[6] = __hfma2(w2, h2(m1.z), am[6]);
            am[7] = __hfma2(w2, h2(m1.w), am[7]);
            uint4 s0 = *(const uint4*)&Hsq[sA];
            uint4 s1 = *(const uint4*)&Hsq[sA ^ 4];
            as[0] = __hfma2(w2, h2(s0.x), as[0]);
            as[1] = __hfma2(w2, h2(s0.y), as[1]);
            as[2] = __hfma2(w2, h2(s0.z), as[2]);
            as[3] = __hfma2(w2, h2(s0.w), as[3]);
            as[4] = __hfma2(w2, h2(s1.x), as[4]);
            as[5] = __hfma2(w2, h2(s1.y), as[5]);
            as[6] = __hfma2(w2, h2(s1.z), as[6]);
            as[7] = __hfma2(w2, h2(s1.w), as[7]);
            int sX = row * (TS_C/2) + ((cg * 4) ^ ((row & 7) << 2));
            uint4 xq = *(const uint4*)&Hxy[sX];
            ax[0] = __hfma2(w2, h2(xq.x), ax[0]);
            ax[1] = __hfma2(w2, h2(xq.y), ax[1]);
            ax[2] = __hfma2(w2, h2(xq.z), ax[2]);
            ax[3] = __hfma2(w2, h2(xq.w), ax[3]);
        }
        #pragma unroll
        for (int e = 0; e < 8; ++e) {
            float mx  = __low2float(am[e]);
            float my  = __high2float(am[e]);
            float exx = __low2float(as[e]);
            float eyy = __high2float(as[e]);
            float exy = (e & 1) ? __high2float(ax[e >> 1]) : __low2float(ax[e >> 1]);
            float mxx = mx * mx, myy = my * my, mxy = mx * my;
            float vx  = exx - mxx;
            float vy  = eyy - myy;
            float vxy = exy - mxy;
            float num = (2.0f * mxy + C1F) * (2.0f * vxy + C2F);
            float den = (mxx + myy + C1F) * (vx + vy + C2F);
            ssum = fmaf(num, __builtin_amdgcn_rcpf(den), ssum);
        }
    }

    // ---- Block reduction (deterministic) ----
    #pragma unroll
    for (int off = 32; off > 0; off >>= 1)
        ssum += __shfl_down(ssum, off, 64);
    if ((tid & 63) == 0) red[tid >> 6] = ssum;
    __syncthreads();
    if (tid == 0) {
        float tot = red[0] + red[1] + red[2] + red[3];
        int bi = (blockIdx.z * gridDim.y + blockIdx.y) * gridDim.x + blockIdx.x;
        partial[bi] = tot;
    }
}

__global__ __launch_bounds__(1024)
void ssim_final(const float* __restrict__ partial, float* __restrict__ out) {
    __shared__ float red[16];
    float s = 0.0f;
    for (int i = threadIdx.x; i < NBLK; i += 1024) s += partial[i];
    #pragma unroll
    for (int off = 32; off > 0; off >>= 1)
        s += __shfl_down(s, off, 64);
    if ((threadIdx.x & 63) == 0) red[threadIdx.x >> 6] = s;
    __syncthreads();
    if (threadIdx.x == 0) {
        float tot = 0.0f;
        #pragma unroll
        for (int i = 0; i < 16; ++i) tot += red[i];
        out[0] = 1.0f - tot * (1.0f / 16777216.0f);
    }
}

extern "C" void kernel_launch(void* const* d_in, const int* in_sizes, int n_in,
                              void* d_out, int out_size, void* d_ws, size_t ws_size,
                              hipStream_t stream) {
    const float* x = (const float*)d_in[0];
    const float* y = (const float*)d_in[1];
    float* out     = (float*)d_out;
    float* partial = (float*)d_ws;   // NBLK floats = 32 KB

    dim3 grid(IMG / TS_C, IMG / TS_R, NIMG);   // (8, 16, 64)
    ssim_main<<<grid, 256, 0, stream>>>(x, y, partial);
    ssim_final<<<1, 1024, 0, stream>>>(partial, out);
}